// Round 20
// baseline (254.558 us; speedup 1.0000x reference)
//
#include <hip/hip_runtime.h>
#include <hip/hip_bf16.h>
#include <stdint.h>

typedef __attribute__((ext_vector_type(8))) short short8;
typedef __attribute__((ext_vector_type(4))) float floatx4;
typedef __attribute__((ext_vector_type(2))) unsigned int uint2v;

#define DEV static __device__ __forceinline__
#define FENCE() asm volatile("" ::: "memory")

DEV unsigned short f2bs(float f) {           // f32 -> bf16 bits, RNE
  union { float f; unsigned u; } v; v.f = f;
  unsigned u = v.u;
  u += 0x7fffu + ((u >> 16) & 1u);
  return (unsigned short)(u >> 16);
}
DEV float bs2f(unsigned short s) {
  union { unsigned u; float f; } v; v.u = ((unsigned)s) << 16;
  return v.f;
}
DEV unsigned pack2(float a, float b) {
  return (unsigned)f2bs(a) | ((unsigned)f2bs(b) << 16);
}

DEV void gload_lds16(const void* g, void* l) {
  __builtin_amdgcn_global_load_lds(
      (const __attribute__((address_space(1))) void*)g,
      (__attribute__((address_space(3))) void*)l, 16, 0, 0);
}

static constexpr int Hdim = 1024;
static constexpr int KDim = 512;
static constexpr int NH = 16;
static constexpr int HK = 32;
static constexpr int HV = 64;
static constexpr int Mtok = 4 * 8192;

// ---------- merged prep: 3x weight f32->bf16 + S^T (one launch) ----------
DEV void cvt4(const float4* __restrict__ in, uint2v* __restrict__ out, int i) {
  float4 v = in[i];
  uint2v o;
  o.x = pack2(v.x, v.y);
  o.y = pack2(v.z, v.w);
  out[i] = o;
}

__global__ __launch_bounds__(256) void k_prep(
    const float* __restrict__ qw, const float* __restrict__ gw,
    const float* __restrict__ ow, const float* __restrict__ S,
    uint2v* __restrict__ qwb, uint2v* __restrict__ gwb,
    uint2v* __restrict__ owb, unsigned short* __restrict__ St) {
  int i = blockIdx.x * 256 + threadIdx.x;
  if (i < 131072) {
    cvt4((const float4*)qw, qwb, i);
    return;
  }
  i -= 131072;
  if (i < 262144) {
    cvt4((const float4*)gw, gwb, i);
    return;
  }
  i -= 262144;
  if (i < 262144) {
    cvt4((const float4*)ow, owb, i);
    return;
  }
  i -= 262144;
  // S -> S^T bf16: St[b][h][v][k] = S[b][h][k][v]
  int k = i & 31, v = (i >> 5) & 63, bh = i >> 11;
  St[i] = f2bs(S[(size_t)(bh * HK + k) * HV + v]);
}

// ---------- rmsnorm(hidden) -> X bf16 : one WAVE per token ----------
__global__ __launch_bounds__(256) void k_rmsnorm(const float* __restrict__ hs,
                                                 const float* __restrict__ nw,
                                                 uint2v* __restrict__ X) {
  const int lane = threadIdx.x & 63;
  const int token = blockIdx.x * 4 + (threadIdx.x >> 6);
  const float4* hp = (const float4*)(hs + (size_t)token * Hdim);
  float4 h[4];
  float ss = 0.f;
#pragma unroll
  for (int i = 0; i < 4; ++i) {
    h[i] = hp[i * 64 + lane];
    ss += h[i].x * h[i].x + h[i].y * h[i].y + h[i].z * h[i].z +
          h[i].w * h[i].w;
  }
#pragma unroll
  for (int off = 1; off < 64; off <<= 1) ss += __shfl_xor(ss, off, 64);
  const float sc = rsqrtf(ss * (1.0f / Hdim) + 1e-5f);
#pragma unroll
  for (int i = 0; i < 4; ++i) {
    float4 w = ((const float4*)nw)[i * 64 + lane];
    uint2v o;
    o.x = pack2(h[i].x * sc * w.x, h[i].y * sc * w.y);
    o.y = pack2(h[i].z * sc * w.z, h[i].w * sc * w.w);
    X[(size_t)token * 256 + i * 64 + lane] = o;
  }
}

// ---------- 128^2 / BK=64 GEMM core (r9-proven; frozen) --------------------
// T2 swizzle both sides: linear gload_lds dest + pre-swizzled global source
// col; read XOR (frr&7)*8 (0-conflict verified r4/r5/r8/r9).
// LDS layout (shorts): As0 [0,8K) As1 [8K,16K) Bs0 [16K,24K) Bs1 [24K,32K)
// -- TOTAL 32768 shorts = 64 KB. (r19 bug: passing a 32 KB buffer put the
// B-slots out of bounds. The buffer MUST be 64 KB.)
// 2-phase: STAGE(t+1) issued BEFORE compute(t); one vmcnt(0)+barrier per
// K-step AFTER compute. No setprio (r17: -5us, m190 regime gate confirmed).
DEV void gemm128d(const unsigned short* __restrict__ A,
                  const unsigned short* __restrict__ Bw, const int K,
                  const int m0, const int n0, unsigned short* LDS,
                  floatx4 (&acc)[4][4], const int tid) {
  const int lane = tid & 63;
  const int w = tid >> 6;
  const int wr = w >> 1, wc = w & 1;
  const int frr = lane & 15;
  const int frk = (lane >> 4) * 8;
  const int aswz = (frr & 7) * 8;
  const int r_a = tid >> 3;                         // 0..31
  const int c_src = ((tid & 7) ^ (r_a & 7)) * 8;    // pre-swizzled col
  const unsigned short* Ag = A + (size_t)(m0 + r_a) * K + c_src;
  const unsigned short* Bg = Bw + (size_t)(n0 + r_a) * K + c_src;
  const int NT = K >> 6;

  {
    char* AsD = (char*)LDS + tid * 16;
    char* BsD = (char*)(LDS + 16384) + tid * 16;
#pragma unroll
    for (int i = 0; i < 4; ++i) {
      gload_lds16(Ag + (size_t)i * 32 * K, AsD + i * 4096);
      gload_lds16(Bg + (size_t)i * 32 * K, BsD + i * 4096);
    }
  }
  asm volatile("s_waitcnt vmcnt(0)" ::: "memory");
  __builtin_amdgcn_s_barrier();
  FENCE();

  int cur = 0;
  for (int t = 0; t < NT; ++t) {
    if (t + 1 < NT) {
      char* AsD = (char*)(LDS + (cur ^ 1) * 8192) + tid * 16;
      char* BsD = (char*)(LDS + 16384 + (cur ^ 1) * 8192) + tid * 16;
      const int k0 = (t + 1) * 64;
#pragma unroll
      for (int i = 0; i < 4; ++i) {
        gload_lds16(Ag + (size_t)i * 32 * K + k0, AsD + i * 4096);
        gload_lds16(Bg + (size_t)i * 32 * K + k0, BsD + i * 4096);
      }
    }
    const unsigned short* Asb = LDS + cur * 8192;
    const unsigned short* Bsb = LDS + 16384 + cur * 8192;
#pragma unroll
    for (int kk = 0; kk < 2; ++kk) {
      short8 a[4], b[4];
#pragma unroll
      for (int mi = 0; mi < 4; ++mi)
        a[mi] = *(const short8*)
            &Asb[(wr * 64 + mi * 16 + frr) * 64 + ((kk * 32 + frk) ^ aswz)];
#pragma unroll
      for (int ni = 0; ni < 4; ++ni)
        b[ni] = *(const short8*)
            &Bsb[(wc * 64 + ni * 16 + frr) * 64 + ((kk * 32 + frk) ^ aswz)];
#pragma unroll
      for (int mi = 0; mi < 4; ++mi)
#pragma unroll
        for (int ni = 0; ni < 4; ++ni)
          acc[mi][ni] = __builtin_amdgcn_mfma_f32_16x16x32_bf16(
              a[mi], b[ni], acc[mi][ni], 0, 0, 0);
    }
    if (t + 1 < NT) {
      asm volatile("s_waitcnt vmcnt(0)" ::: "memory");
      __builtin_amdgcn_s_barrier();
      FENCE();
    }
    cur ^= 1;
  }
  __syncthreads();
}

// ---------- fused gate+o:  out = sigmoid(X@gw^T) * (Ob@ow^T), f32 ----------
// 1D grid 2048; XCD-chunked, m-major within chunk (A-tile L2-resident).
// Non-temporal epilogue stores: output is write-once; don't evict L2 panels.
__global__ __launch_bounds__(256, 2) void k_fused_go(
    const unsigned short* __restrict__ X, const unsigned short* __restrict__ Ob,
    const unsigned short* __restrict__ gwb,
    const unsigned short* __restrict__ owb, float* __restrict__ out) {
  __shared__ unsigned short LDS[4 * 128 * 64];   // 64 KB (2 slots x A,B)
  const int tid = threadIdx.x;
  const int lane = tid & 63;
  const int w = tid >> 6;
  const int wr = w >> 1, wc = w & 1;
  const int bid = blockIdx.x;               // nwg = 2048 (multiple of 8)
  const int v = (bid & 7) * 256 + (bid >> 3);
  const int m0 = (v >> 3) * 128;            // m-major within XCD chunk
  const int n0 = (v & 7) * 128;

  floatx4 acc[4][4];
#pragma unroll
  for (int i = 0; i < 4; ++i)
#pragma unroll
    for (int j = 0; j < 4; ++j) acc[i][j] = (floatx4){0.f, 0.f, 0.f, 0.f};

  // pass 1: gate
  gemm128d(X, gwb, Hdim, m0, n0, LDS, acc, tid);

  // sigmoid -> packed bf16 stash
  unsigned pg[4][4][2];
#pragma unroll
  for (int mi = 0; mi < 4; ++mi)
#pragma unroll
    for (int ni = 0; ni < 4; ++ni) {
      float s0 = 1.0f / (1.0f + __expf(-acc[mi][ni][0]));
      float s1 = 1.0f / (1.0f + __expf(-acc[mi][ni][1]));
      float s2 = 1.0f / (1.0f + __expf(-acc[mi][ni][2]));
      float s3 = 1.0f / (1.0f + __expf(-acc[mi][ni][3]));
      pg[mi][ni][0] = pack2(s0, s1);
      pg[mi][ni][1] = pack2(s2, s3);
      acc[mi][ni] = (floatx4){0.f, 0.f, 0.f, 0.f};
    }

  // pass 2: o-proj
  gemm128d(Ob, owb, Hdim, m0, n0, LDS, acc, tid);

  // epilogue: C/D layout col = lane&15, row = (lane>>4)*4 + r
  const int rb = (lane >> 4) * 4;
#pragma unroll
  for (int mi = 0; mi < 4; ++mi)
#pragma unroll
    for (int ni = 0; ni < 4; ++ni) {
      const int n = n0 + wc * 64 + ni * 16 + (lane & 15);
#pragma unroll
      for (int r = 0; r < 4; ++r) {
        const int m = m0 + wr * 64 + mi * 16 + rb + r;
        float g = bs2f((unsigned short)(pg[mi][ni][r >> 1] >> ((r & 1) * 16)));
        __builtin_nontemporal_store(g * acc[mi][ni][r],
                                    &out[(size_t)m * Hdim + n]);
      }
    }
}

// ---------- fused q-path (r18-proven, 64 KB LDS): q -> L2-norm -> @S -> rms -
__global__ __launch_bounds__(256, 2) void k_fused_q(
    const unsigned short* __restrict__ X, const unsigned short* __restrict__ qwb,
    const unsigned short* __restrict__ St, const float* __restrict__ vnw,
    unsigned short* __restrict__ Ob) {
  __shared__ unsigned short LD[4 * 128 * 64];  // 64 KB; qt overlays [0,16K)
  const int tid = threadIdx.x;
  const int lane = tid & 63;
  const int w = tid >> 6;
  const int wr = w >> 1, wc = w & 1;
  const int bid = blockIdx.x;               // nwg = 1024
  const int v = (bid & 7) * 128 + (bid >> 3);
  const int m0 = (v >> 2) * 128;
  const int n0 = (v & 3) * 128;             // q-dim base; heads h0..h0+3
  const int h0 = n0 >> 5;
  const int batch = m0 >> 13;               // 8192 tokens per batch

  floatx4 acc[4][4];
#pragma unroll
  for (int i = 0; i < 4; ++i)
#pragma unroll
    for (int j = 0; j < 4; ++j) acc[i][j] = (floatx4){0.f, 0.f, 0.f, 0.f};

  gemm128d(X, qwb, Hdim, m0, n0, LD, acc, tid);

  const int rb = (lane >> 4) * 4;
  const int frr = lane & 15;
#pragma unroll
  for (int mi = 0; mi < 4; ++mi)
#pragma unroll
    for (int p = 0; p < 2; ++p) {
#pragma unroll
      for (int r = 0; r < 4; ++r) {
        float v0 = acc[mi][2 * p][r], v1 = acc[mi][2 * p + 1][r];
        float ss = v0 * v0 + v1 * v1;
        ss += __shfl_xor(ss, 1, 64);
        ss += __shfl_xor(ss, 2, 64);
        ss += __shfl_xor(ss, 4, 64);
        ss += __shfl_xor(ss, 8, 64);
        const float inv = 1.0f / fmaxf(sqrtf(ss), 1e-12f);
        const int m = wr * 64 + mi * 16 + rb + r;
        const int c0 = wc * 64 + p * 32 + frr;
        const int sw = (m & 7) * 8;
        LD[m * 128 + (c0 ^ sw)] = f2bs(v0 * inv);
        LD[m * 128 + ((c0 + 16) ^ sw)] = f2bs(v1 * inv);
      }
    }
  __syncthreads();

  const int frk = (lane >> 4) * 8;
  float wv[4];
#pragma unroll
  for (int ni = 0; ni < 4; ++ni) wv[ni] = vnw[ni * 16 + frr];

#pragma unroll
  for (int hh = 0; hh < 4; ++hh) {
    const unsigned short* Sp = St + (size_t)(batch * NH + h0 + hh) * (HV * HK);
    short8 bfr[4];
#pragma unroll
    for (int ni = 0; ni < 4; ++ni)
      bfr[ni] = *(const short8*)&Sp[(ni * 16 + frr) * HK + frk];
    floatx4 acc2[2][4];
#pragma unroll
    for (int i = 0; i < 2; ++i)
#pragma unroll
      for (int j = 0; j < 4; ++j) acc2[i][j] = (floatx4){0.f, 0.f, 0.f, 0.f};
    short8 af[2];
#pragma unroll
    for (int mi2 = 0; mi2 < 2; ++mi2) {
      const int m = w * 32 + mi2 * 16 + frr;
      af[mi2] = *(const short8*)&LD[m * 128 + ((hh * 32 + frk) ^ ((m & 7) * 8))];
    }
#pragma unroll
    for (int mi2 = 0; mi2 < 2; ++mi2)
#pragma unroll
      for (int ni = 0; ni < 4; ++ni)
        acc2[mi2][ni] = __builtin_amdgcn_mfma_f32_16x16x32_bf16(
            af[mi2], bfr[ni], acc2[mi2][ni], 0, 0, 0);

#pragma unroll
    for (int mi2 = 0; mi2 < 2; ++mi2)
#pragma unroll
      for (int r = 0; r < 4; ++r) {
        float ss2 = 0.f;
#pragma unroll
        for (int ni = 0; ni < 4; ++ni) ss2 += acc2[mi2][ni][r] * acc2[mi2][ni][r];
        ss2 += __shfl_xor(ss2, 1, 64);
        ss2 += __shfl_xor(ss2, 2, 64);
        ss2 += __shfl_xor(ss2, 4, 64);
        ss2 += __shfl_xor(ss2, 8, 64);
        const float sc = rsqrtf(ss2 * (1.0f / HV) + 1e-5f);
        const int m = m0 + w * 32 + mi2 * 16 + rb + r;
        unsigned short* Op = Ob + (size_t)m * Hdim + (h0 + hh) * HV;
#pragma unroll
        for (int ni = 0; ni < 4; ++ni)
          Op[ni * 16 + frr] = f2bs(acc2[mi2][ni][r] * sc * wv[ni]);
      }
  }
}

extern "C" void kernel_launch(void* const* d_in, const int* in_sizes, int n_in,
                              void* d_out, int out_size, void* d_ws, size_t ws_size,
                              hipStream_t stream) {
  const float* hs = (const float*)d_in[0];
  const float* Srec = (const float*)d_in[1];
  const float* nw = (const float*)d_in[2];
  const float* qw = (const float*)d_in[3];
  const float* vnw = (const float*)d_in[4];
  const float* ow = (const float*)d_in[5];
  const float* gw = (const float*)d_in[6];

  char* ws = (char*)d_ws;
  unsigned short* X = (unsigned short*)(ws);                          // 64 MB bf16 [M,H]
  unsigned short* Ob = (unsigned short*)(ws + ((size_t)64 << 20));    // 64 MB bf16 [M,VD]
  unsigned short* qwb = (unsigned short*)(ws + ((size_t)128 << 20));  // 1 MB
  unsigned short* gwb = (unsigned short*)(ws + ((size_t)129 << 20));  // 2 MB
  unsigned short* owb = (unsigned short*)(ws + ((size_t)131 << 20));  // 2 MB
  unsigned short* Stb = (unsigned short*)(ws + ((size_t)133 << 20));  // 256 KB

  // merged prep: weights f32 -> bf16 + S^T (one launch, 3072 blocks)
  k_prep<<<3072, 256, 0, stream>>>(qw, gw, ow, Srec, (uint2v*)qwb,
                                   (uint2v*)gwb, (uint2v*)owb, Stb);

  // x = rmsnorm(hidden) -> bf16  (wave-per-token)
  k_rmsnorm<<<Mtok / 4, 256, 0, stream>>>(hs, nw, (uint2v*)X);

  // fused q path -> Ob
  k_fused_q<<<(Mtok / 128) * (KDim / 128), 256, 0, stream>>>(
      X, qwb, Stb, vnw, Ob);

  // fused gate+o -> d_out f32
  k_fused_go<<<(Mtok / 128) * (Hdim / 128), 256, 0, stream>>>(
      X, Ob, gwb, owb, (float*)d_out);
}

// Round 21
// 252.941 us; speedup vs baseline: 1.0064x; 1.0064x over previous
//
#include <hip/hip_runtime.h>
#include <hip/hip_bf16.h>
#include <stdint.h>

typedef __attribute__((ext_vector_type(8))) short short8;
typedef __attribute__((ext_vector_type(4))) float floatx4;
typedef __attribute__((ext_vector_type(2))) unsigned int uint2v;

#define DEV static __device__ __forceinline__
#define FENCE() asm volatile("" ::: "memory")

DEV unsigned short f2bs(float f) {           // f32 -> bf16 bits, RNE
  union { float f; unsigned u; } v; v.f = f;
  unsigned u = v.u;
  u += 0x7fffu + ((u >> 16) & 1u);
  return (unsigned short)(u >> 16);
}
DEV float bs2f(unsigned short s) {
  union { unsigned u; float f; } v; v.u = ((unsigned)s) << 16;
  return v.f;
}
DEV unsigned pack2(float a, float b) {
  return (unsigned)f2bs(a) | ((unsigned)f2bs(b) << 16);
}

DEV void gload_lds16(const void* g, void* l) {
  __builtin_amdgcn_global_load_lds(
      (const __attribute__((address_space(1))) void*)g,
      (__attribute__((address_space(3))) void*)l, 16, 0, 0);
}

static constexpr int Hdim = 1024;
static constexpr int KDim = 512;
static constexpr int NH = 16;
static constexpr int HK = 32;
static constexpr int HV = 64;
static constexpr int Mtok = 4 * 8192;

// ---------- merged prep: 3x weight f32->bf16 + S^T (one launch) ----------
DEV void cvt4(const float4* __restrict__ in, uint2v* __restrict__ out, int i) {
  float4 v = in[i];
  uint2v o;
  o.x = pack2(v.x, v.y);
  o.y = pack2(v.z, v.w);
  out[i] = o;
}

__global__ __launch_bounds__(256) void k_prep(
    const float* __restrict__ qw, const float* __restrict__ gw,
    const float* __restrict__ ow, const float* __restrict__ S,
    uint2v* __restrict__ qwb, uint2v* __restrict__ gwb,
    uint2v* __restrict__ owb, unsigned short* __restrict__ St) {
  int i = blockIdx.x * 256 + threadIdx.x;
  if (i < 131072) {
    cvt4((const float4*)qw, qwb, i);
    return;
  }
  i -= 131072;
  if (i < 262144) {
    cvt4((const float4*)gw, gwb, i);
    return;
  }
  i -= 262144;
  if (i < 262144) {
    cvt4((const float4*)ow, owb, i);
    return;
  }
  i -= 262144;
  // S -> S^T bf16: St[b][h][v][k] = S[b][h][k][v]
  int k = i & 31, v = (i >> 5) & 63, bh = i >> 11;
  St[i] = f2bs(S[(size_t)(bh * HK + k) * HV + v]);
}

// ---------- rmsnorm(hidden) -> X bf16 : one WAVE per token ----------
__global__ __launch_bounds__(256) void k_rmsnorm(const float* __restrict__ hs,
                                                 const float* __restrict__ nw,
                                                 uint2v* __restrict__ X) {
  const int lane = threadIdx.x & 63;
  const int token = blockIdx.x * 4 + (threadIdx.x >> 6);
  const float4* hp = (const float4*)(hs + (size_t)token * Hdim);
  float4 h[4];
  float ss = 0.f;
#pragma unroll
  for (int i = 0; i < 4; ++i) {
    h[i] = hp[i * 64 + lane];
    ss += h[i].x * h[i].x + h[i].y * h[i].y + h[i].z * h[i].z +
          h[i].w * h[i].w;
  }
#pragma unroll
  for (int off = 1; off < 64; off <<= 1) ss += __shfl_xor(ss, off, 64);
  const float sc = rsqrtf(ss * (1.0f / Hdim) + 1e-5f);
#pragma unroll
  for (int i = 0; i < 4; ++i) {
    float4 w = ((const float4*)nw)[i * 64 + lane];
    uint2v o;
    o.x = pack2(h[i].x * sc * w.x, h[i].y * sc * w.y);
    o.y = pack2(h[i].z * sc * w.z, h[i].w * sc * w.w);
    X[(size_t)token * 256 + i * 64 + lane] = o;
  }
}

// ---------- 128^2 / BK=64 GEMM core (r9-proven; frozen) --------------------
// T2 swizzle both sides: linear gload_lds dest + pre-swizzled global source
// col; read XOR (frr&7)*8 (0-conflict verified r4/r5/r8/r9).
// LDS layout (shorts): As0 [0,8K) As1 [8K,16K) Bs0 [16K,24K) Bs1 [24K,32K)
// -- TOTAL 32768 shorts = 64 KB (r19 lesson: the buffer MUST be 64 KB).
// 2-phase: STAGE(t+1) issued BEFORE compute(t); one vmcnt(0)+barrier per
// K-step AFTER compute. No setprio (r17: -5us, m190 regime gate confirmed).
DEV void gemm128d(const unsigned short* __restrict__ A,
                  const unsigned short* __restrict__ Bw, const int K,
                  const int m0, const int n0, unsigned short* LDS,
                  floatx4 (&acc)[4][4], const int tid) {
  const int lane = tid & 63;
  const int w = tid >> 6;
  const int wr = w >> 1, wc = w & 1;
  const int frr = lane & 15;
  const int frk = (lane >> 4) * 8;
  const int aswz = (frr & 7) * 8;
  const int r_a = tid >> 3;                         // 0..31
  const int c_src = ((tid & 7) ^ (r_a & 7)) * 8;    // pre-swizzled col
  const unsigned short* Ag = A + (size_t)(m0 + r_a) * K + c_src;
  const unsigned short* Bg = Bw + (size_t)(n0 + r_a) * K + c_src;
  const int NT = K >> 6;

  {
    char* AsD = (char*)LDS + tid * 16;
    char* BsD = (char*)(LDS + 16384) + tid * 16;
#pragma unroll
    for (int i = 0; i < 4; ++i) {
      gload_lds16(Ag + (size_t)i * 32 * K, AsD + i * 4096);
      gload_lds16(Bg + (size_t)i * 32 * K, BsD + i * 4096);
    }
  }
  asm volatile("s_waitcnt vmcnt(0)" ::: "memory");
  __builtin_amdgcn_s_barrier();
  FENCE();

  int cur = 0;
  for (int t = 0; t < NT; ++t) {
    if (t + 1 < NT) {
      char* AsD = (char*)(LDS + (cur ^ 1) * 8192) + tid * 16;
      char* BsD = (char*)(LDS + 16384 + (cur ^ 1) * 8192) + tid * 16;
      const int k0 = (t + 1) * 64;
#pragma unroll
      for (int i = 0; i < 4; ++i) {
        gload_lds16(Ag + (size_t)i * 32 * K + k0, AsD + i * 4096);
        gload_lds16(Bg + (size_t)i * 32 * K + k0, BsD + i * 4096);
      }
    }
    const unsigned short* Asb = LDS + cur * 8192;
    const unsigned short* Bsb = LDS + 16384 + cur * 8192;
#pragma unroll
    for (int kk = 0; kk < 2; ++kk) {
      short8 a[4], b[4];
#pragma unroll
      for (int mi = 0; mi < 4; ++mi)
        a[mi] = *(const short8*)
            &Asb[(wr * 64 + mi * 16 + frr) * 64 + ((kk * 32 + frk) ^ aswz)];
#pragma unroll
      for (int ni = 0; ni < 4; ++ni)
        b[ni] = *(const short8*)
            &Bsb[(wc * 64 + ni * 16 + frr) * 64 + ((kk * 32 + frk) ^ aswz)];
#pragma unroll
      for (int mi = 0; mi < 4; ++mi)
#pragma unroll
        for (int ni = 0; ni < 4; ++ni)
          acc[mi][ni] = __builtin_amdgcn_mfma_f32_16x16x32_bf16(
              a[mi], b[ni], acc[mi][ni], 0, 0, 0);
    }
    if (t + 1 < NT) {
      asm volatile("s_waitcnt vmcnt(0)" ::: "memory");
      __builtin_amdgcn_s_barrier();
      FENCE();
    }
    cur ^= 1;
  }
  __syncthreads();
}

// ---------- fused gate+o:  out = sigmoid(X@gw^T) * (Ob@ow^T), f32 ----------
// 1D grid 2048; XCD-chunked, m-major within chunk (A-tile L2-resident).
// Plain epilogue stores (r20: non-temporal grew WRITE 131->190MB, +2us).
__global__ __launch_bounds__(256, 2) void k_fused_go(
    const unsigned short* __restrict__ X, const unsigned short* __restrict__ Ob,
    const unsigned short* __restrict__ gwb,
    const unsigned short* __restrict__ owb, float* __restrict__ out) {
  __shared__ unsigned short LDS[4 * 128 * 64];   // 64 KB (2 slots x A,B)
  const int tid = threadIdx.x;
  const int lane = tid & 63;
  const int w = tid >> 6;
  const int wr = w >> 1, wc = w & 1;
  const int bid = blockIdx.x;               // nwg = 2048 (multiple of 8)
  const int v = (bid & 7) * 256 + (bid >> 3);
  const int m0 = (v >> 3) * 128;            // m-major within XCD chunk
  const int n0 = (v & 7) * 128;

  floatx4 acc[4][4];
#pragma unroll
  for (int i = 0; i < 4; ++i)
#pragma unroll
    for (int j = 0; j < 4; ++j) acc[i][j] = (floatx4){0.f, 0.f, 0.f, 0.f};

  // pass 1: gate
  gemm128d(X, gwb, Hdim, m0, n0, LDS, acc, tid);

  // sigmoid -> packed bf16 stash
  unsigned pg[4][4][2];
#pragma unroll
  for (int mi = 0; mi < 4; ++mi)
#pragma unroll
    for (int ni = 0; ni < 4; ++ni) {
      float s0 = 1.0f / (1.0f + __expf(-acc[mi][ni][0]));
      float s1 = 1.0f / (1.0f + __expf(-acc[mi][ni][1]));
      float s2 = 1.0f / (1.0f + __expf(-acc[mi][ni][2]));
      float s3 = 1.0f / (1.0f + __expf(-acc[mi][ni][3]));
      pg[mi][ni][0] = pack2(s0, s1);
      pg[mi][ni][1] = pack2(s2, s3);
      acc[mi][ni] = (floatx4){0.f, 0.f, 0.f, 0.f};
    }

  // pass 2: o-proj
  gemm128d(Ob, owb, Hdim, m0, n0, LDS, acc, tid);

  // epilogue: C/D layout col = lane&15, row = (lane>>4)*4 + r
  const int rb = (lane >> 4) * 4;
#pragma unroll
  for (int mi = 0; mi < 4; ++mi)
#pragma unroll
    for (int ni = 0; ni < 4; ++ni) {
      const int n = n0 + wc * 64 + ni * 16 + (lane & 15);
#pragma unroll
      for (int r = 0; r < 4; ++r) {
        const int m = m0 + wr * 64 + mi * 16 + rb + r;
        float g = bs2f((unsigned short)(pg[mi][ni][r >> 1] >> ((r & 1) * 16)));
        out[(size_t)m * Hdim + n] = g * acc[mi][ni][r];
      }
    }
}

// ---------- fused q-path (r18-proven, 64 KB LDS): q -> L2-norm -> @S -> rms -
__global__ __launch_bounds__(256, 2) void k_fused_q(
    const unsigned short* __restrict__ X, const unsigned short* __restrict__ qwb,
    const unsigned short* __restrict__ St, const float* __restrict__ vnw,
    unsigned short* __restrict__ Ob) {
  __shared__ unsigned short LD[4 * 128 * 64];  // 64 KB; qt overlays [0,16K)
  const int tid = threadIdx.x;
  const int lane = tid & 63;
  const int w = tid >> 6;
  const int wr = w >> 1, wc = w & 1;
  const int bid = blockIdx.x;               // nwg = 1024
  const int v = (bid & 7) * 128 + (bid >> 3);
  const int m0 = (v >> 2) * 128;
  const int n0 = (v & 3) * 128;             // q-dim base; heads h0..h0+3
  const int h0 = n0 >> 5;
  const int batch = m0 >> 13;               // 8192 tokens per batch

  floatx4 acc[4][4];
#pragma unroll
  for (int i = 0; i < 4; ++i)
#pragma unroll
    for (int j = 0; j < 4; ++j) acc[i][j] = (floatx4){0.f, 0.f, 0.f, 0.f};

  gemm128d(X, qwb, Hdim, m0, n0, LD, acc, tid);

  const int rb = (lane >> 4) * 4;
  const int frr = lane & 15;
#pragma unroll
  for (int mi = 0; mi < 4; ++mi)
#pragma unroll
    for (int p = 0; p < 2; ++p) {
#pragma unroll
      for (int r = 0; r < 4; ++r) {
        float v0 = acc[mi][2 * p][r], v1 = acc[mi][2 * p + 1][r];
        float ss = v0 * v0 + v1 * v1;
        ss += __shfl_xor(ss, 1, 64);
        ss += __shfl_xor(ss, 2, 64);
        ss += __shfl_xor(ss, 4, 64);
        ss += __shfl_xor(ss, 8, 64);
        const float inv = 1.0f / fmaxf(sqrtf(ss), 1e-12f);
        const int m = wr * 64 + mi * 16 + rb + r;
        const int c0 = wc * 64 + p * 32 + frr;
        const int sw = (m & 7) * 8;
        LD[m * 128 + (c0 ^ sw)] = f2bs(v0 * inv);
        LD[m * 128 + ((c0 + 16) ^ sw)] = f2bs(v1 * inv);
      }
    }
  __syncthreads();

  const int frk = (lane >> 4) * 8;
  float wv[4];
#pragma unroll
  for (int ni = 0; ni < 4; ++ni) wv[ni] = vnw[ni * 16 + frr];

#pragma unroll
  for (int hh = 0; hh < 4; ++hh) {
    const unsigned short* Sp = St + (size_t)(batch * NH + h0 + hh) * (HV * HK);
    short8 bfr[4];
#pragma unroll
    for (int ni = 0; ni < 4; ++ni)
      bfr[ni] = *(const short8*)&Sp[(ni * 16 + frr) * HK + frk];
    floatx4 acc2[2][4];
#pragma unroll
    for (int i = 0; i < 2; ++i)
#pragma unroll
      for (int j = 0; j < 4; ++j) acc2[i][j] = (floatx4){0.f, 0.f, 0.f, 0.f};
    short8 af[2];
#pragma unroll
    for (int mi2 = 0; mi2 < 2; ++mi2) {
      const int m = w * 32 + mi2 * 16 + frr;
      af[mi2] = *(const short8*)&LD[m * 128 + ((hh * 32 + frk) ^ ((m & 7) * 8))];
    }
#pragma unroll
    for (int mi2 = 0; mi2 < 2; ++mi2)
#pragma unroll
      for (int ni = 0; ni < 4; ++ni)
        acc2[mi2][ni] = __builtin_amdgcn_mfma_f32_16x16x32_bf16(
            af[mi2], bfr[ni], acc2[mi2][ni], 0, 0, 0);

#pragma unroll
    for (int mi2 = 0; mi2 < 2; ++mi2)
#pragma unroll
      for (int r = 0; r < 4; ++r) {
        float ss2 = 0.f;
#pragma unroll
        for (int ni = 0; ni < 4; ++ni) ss2 += acc2[mi2][ni][r] * acc2[mi2][ni][r];
        ss2 += __shfl_xor(ss2, 1, 64);
        ss2 += __shfl_xor(ss2, 2, 64);
        ss2 += __shfl_xor(ss2, 4, 64);
        ss2 += __shfl_xor(ss2, 8, 64);
        const float sc = rsqrtf(ss2 * (1.0f / HV) + 1e-5f);
        const int m = m0 + w * 32 + mi2 * 16 + rb + r;
        unsigned short* Op = Ob + (size_t)m * Hdim + (h0 + hh) * HV;
#pragma unroll
        for (int ni = 0; ni < 4; ++ni)
          Op[ni * 16 + frr] = f2bs(acc2[mi2][ni][r] * sc * wv[ni]);
      }
  }
}

extern "C" void kernel_launch(void* const* d_in, const int* in_sizes, int n_in,
                              void* d_out, int out_size, void* d_ws, size_t ws_size,
                              hipStream_t stream) {
  const float* hs = (const float*)d_in[0];
  const float* Srec = (const float*)d_in[1];
  const float* nw = (const float*)d_in[2];
  const float* qw = (const float*)d_in[3];
  const float* vnw = (const float*)d_in[4];
  const float* ow = (const float*)d_in[5];
  const float* gw = (const float*)d_in[6];

  char* ws = (char*)d_ws;
  unsigned short* X = (unsigned short*)(ws);                          // 64 MB bf16 [M,H]
  unsigned short* Ob = (unsigned short*)(ws + ((size_t)64 << 20));    // 64 MB bf16 [M,VD]
  unsigned short* qwb = (unsigned short*)(ws + ((size_t)128 << 20));  // 1 MB
  unsigned short* gwb = (unsigned short*)(ws + ((size_t)129 << 20));  // 2 MB
  unsigned short* owb = (unsigned short*)(ws + ((size_t)131 << 20));  // 2 MB
  unsigned short* Stb = (unsigned short*)(ws + ((size_t)133 << 20));  // 256 KB

  // merged prep: weights f32 -> bf16 + S^T (one launch, 3072 blocks)
  k_prep<<<3072, 256, 0, stream>>>(qw, gw, ow, Srec, (uint2v*)qwb,
                                   (uint2v*)gwb, (uint2v*)owb, Stb);

  // x = rmsnorm(hidden) -> bf16  (wave-per-token)
  k_rmsnorm<<<Mtok / 4, 256, 0, stream>>>(hs, nw, (uint2v*)X);

  // fused q path -> Ob
  k_fused_q<<<(Mtok / 128) * (KDim / 128), 256, 0, stream>>>(
      X, qwb, Stb, vnw, Ob);

  // fused gate+o -> d_out f32
  k_fused_go<<<(Mtok / 128) * (Hdim / 128), 256, 0, stream>>>(
      X, Ob, gwb, owb, (float*)d_out);
}